// Round 18
// baseline (10958.887 us; speedup 1.0000x reference)
//
#include <hip/hip_runtime.h>

#define H 64
#define G4 256   // 4*H
#define CS 512   // timesteps per chunk
#define NC 32    // chunks: T = NC*CS
#define PB 16    // proj blocks per layer-projection
#define TPB (CS / PB)  // 32 timesteps per proj block
#define LOG2E 1.44269504088896f

typedef _Float16 f16x8 __attribute__((ext_vector_type(8)));
typedef float f32x4 __attribute__((ext_vector_type(4)));
typedef int i32x4 __attribute__((ext_vector_type(4)));
typedef __fp16 p16x2 __attribute__((ext_vector_type(2)));

union I4F { i32x4 i; f16x8 h; };

__device__ __forceinline__ int pack_f16s(float lo, float hi, float sc) {
  union { p16x2 h; int i; } u;
  u.h = __builtin_amdgcn_cvt_pkrtz(lo * sc, hi * sc);
  return u.i;
}
__device__ __forceinline__ int pack_f16(float lo, float hi) {
  union { p16x2 h; int i; } u;
  u.h = __builtin_amdgcn_cvt_pkrtz(lo, hi);
  return u.i;
}
__device__ __forceinline__ float bperm_f(int src_lane, float v) {
  return __int_as_float(
      __builtin_amdgcn_ds_bpermute(src_lane << 2, __float_as_int(v)));
}

// Input projection, cperm-major (pos = u*4 + G), bias folded, gate-scaled
// (tanh gate ×2log2e, sigmoid gates ×-log2e -> scan uses raw exp2+rcp).
__global__ __launch_bounds__(G4) void proj_x(const float* __restrict__ x,
                                             const float* __restrict__ W,
                                             const float* __restrict__ b,
                                             float* __restrict__ xw) {
  const int t = blockIdx.x;
  const int j = threadIdx.x;  // original column = G*64 + u
  const int G = j >> 6, u = j & 63;
  const float sc = (G == 2) ? 2.f * LOG2E : -LOG2E;
  xw[(size_t)t * G4 + u * 4 + G] =
      sc * fmaf(x[2 * t], W[j], fmaf(x[2 * t + 1], W[G4 + j], b[j]));
}

// One pipeline step (launch q). All dependencies cross LAUNCH boundaries.
//   block 0/1/2: scan L0 chunk q / L1 chunk q-2 / L2 chunk q-4
//   blocks 3..18:  proj2 chunk q-1: xw2s = scl*(W2^T h1 + b2)
//   blocks 19..34: proj3 chunk q-3: xw3s = scl*(W3^T h2 + b3)
//
// SCAN = single wave per layer, ALL of U held as MFMA A-fragments parked in
// AGPRs ("+a" asm: AGPR class + unrematerializable opaque def). gfx950 MFMA
// reads A directly from AGPRs (unified file), so the loop's VGPR working
// set is only ~70 regs — under the compiler's observed 132-VGPR ceiling
// that sabotaged r13/r17's "+v" (VGPR-class) versions with in-loop remat.
// 32 MFMAs/step (builtins: compiler keeps hazard handling), lane (n,kg)
// owns unit u = 4n+kg, h redistribution = 16 intra-wave ds_bpermute.
// No LDS, no barrier in the scan.
__global__ __attribute__((amdgpu_flat_work_group_size(G4, G4),
                          amdgpu_waves_per_eu(1, 1)))
void pipe_step(int q, const float* __restrict__ xw1,
               const float* __restrict__ U1, const float* __restrict__ U2,
               const float* __restrict__ U3, const float* __restrict__ W2,
               const float* __restrict__ W3, const float* __restrict__ b2,
               const float* __restrict__ b3, __fp16* __restrict__ h1s,
               __fp16* __restrict__ h2s, float* __restrict__ xw2s,
               float* __restrict__ xw3s, float* __restrict__ hbnd,
               float* __restrict__ cst, float* __restrict__ h3out, int T) {
  const int bid = (int)blockIdx.x;
  const int tid = (int)threadIdx.x;

  // ================= proj blocks (r16-proven) =================
  if (bid >= 3) {
    const int p = bid - 3;
    const int lay = p / PB;             // 0: L1 input, 1: L2 input
    const int pb = p % PB;
    const int chunk = q - 1 - 2 * lay;  // q-1 or q-3
    if (chunk < 0 || chunk >= NC) return;
    const __fp16* hsrc = lay ? h2s : h1s;
    const float* Wm = lay ? W3 : W2;
    const float* bb = lay ? b3 : b2;
    float* dst = (lay ? xw3s : xw2s) + (size_t)(chunk & 1) * CS * G4;
    const int tl0 = pb * TPB;

    __shared__ float sh[TPB * H];
    {
      union { int4 i; __fp16 hh[8]; } uu;
      uu.i = ((const int4*)(hsrc + (size_t)(chunk * CS + tl0) * H))[tid];
      float4 lo = make_float4(uu.hh[0], uu.hh[1], uu.hh[2], uu.hh[3]);
      float4 hi = make_float4(uu.hh[4], uu.hh[5], uu.hh[6], uu.hh[7]);
      ((float4*)sh)[2 * tid] = lo;
      ((float4*)sh)[2 * tid + 1] = hi;
    }
    __syncthreads();

    const int j = tid;
    const int G = j >> 6, u = j & 63;
    const int pos = (u << 2) | G;
    const float scl = (G == 2) ? 2.f * LOG2E : -LOG2E;
    float w[H];
#pragma unroll
    for (int k = 0; k < H; ++k) w[k] = Wm[k * G4 + j];
    const float bj = bb[j];

    for (int tt = 0; tt < TPB; ++tt) {
      const float4* h4 = (const float4*)(sh + tt * H);
      float a0 = bj, a1 = 0.f, a2 = 0.f, a3 = 0.f;
#pragma unroll
      for (int kk = 0; kk < H / 4; ++kk) {
        float4 hv = h4[kk];
        a0 = fmaf(hv.x, w[4 * kk + 0], a0);
        a1 = fmaf(hv.y, w[4 * kk + 1], a1);
        a2 = fmaf(hv.z, w[4 * kk + 2], a2);
        a3 = fmaf(hv.w, w[4 * kk + 3], a3);
      }
      dst[(size_t)(tl0 + tt) * G4 + pos] = scl * ((a0 + a1) + (a2 + a3));
    }
    return;
  }

  // ================= scan blocks: single wave, AGPR weights ============
  const int role = bid;
  const int chunk = q - 2 * role;
  if (chunk < 0 || chunk >= NC) return;
  if (tid >= 64) return;  // one wave only
  const int t0 = chunk * CS;

  const int n = tid & 15;
  const int kg = tid >> 4;
  const int grp = n >> 2;
  const int u_own = 4 * n + kg;  // unique unit per lane

  const float* U = (role == 0) ? U1 : ((role == 1) ? U2 : U3);
  const float scl = ((n & 3) == 2) ? 2.f * LOG2E : -LOG2E;

  // Full U as A-fragments: tile (w,tau), K-tile kap -> 32 i32x4, parked in
  // AGPRs (outside the VGPR budget; MFMA reads A from AGPR directly).
  I4F au[4][4][2];
#pragma unroll
  for (int w = 0; w < 4; ++w) {
#pragma unroll
    for (int tau = 0; tau < 4; ++tau) {
      const int colA = ((n & 3) << 6) | (w << 4) | (tau << 2) | grp;
#pragma unroll
      for (int kap = 0; kap < 2; ++kap) {
        const int k0 = kap * 32 + kg * 8;
        au[w][tau][kap].i = (i32x4){
            pack_f16s(U[(k0 + 0) * G4 + colA], U[(k0 + 1) * G4 + colA], scl),
            pack_f16s(U[(k0 + 2) * G4 + colA], U[(k0 + 3) * G4 + colA], scl),
            pack_f16s(U[(k0 + 4) * G4 + colA], U[(k0 + 5) * G4 + colA], scl),
            pack_f16s(U[(k0 + 6) * G4 + colA], U[(k0 + 7) * G4 + colA], scl)};
        asm volatile("" : "+a"(au[w][tau][kap].i));  // park in AGPR quad
      }
    }
  }

  const float* xbase =
      (role == 0) ? (xw1 + (size_t)t0 * G4)
                  : ((role == 1) ? xw2s : xw3s) + (size_t)(chunk & 1) * CS * G4;
  __fp16* hout = (role == 0) ? h1s : h2s;

  // State restore (cross-launch): c and the B-fragments of h[t0-1].
  float c;
  I4F bf0, bf1;
  if (chunk == 0) {
    c = 0.f;
    bf0.i = (i32x4){0, 0, 0, 0};
    bf1.i = (i32x4){0, 0, 0, 0};
  } else {
    c = cst[role * 64 + u_own];
    const float* hb = hbnd + role * 64;
    float4 lo = *(const float4*)(hb + 8 * kg);
    float4 hi = *(const float4*)(hb + 8 * kg + 4);
    bf0.i = (i32x4){pack_f16(lo.x, lo.y), pack_f16(lo.z, lo.w),
                    pack_f16(hi.x, hi.y), pack_f16(hi.z, hi.w)};
    float4 lo1 = *(const float4*)(hb + 32 + 8 * kg);
    float4 hi1 = *(const float4*)(hb + 32 + 8 * kg + 4);
    bf1.i = (i32x4){pack_f16(lo1.x, lo1.y), pack_f16(lo1.z, lo1.w),
                    pack_f16(hi1.x, hi1.y), pack_f16(hi1.z, hi1.w)};
  }

  f32x4 zero4 = {0.f, 0.f, 0.f, 0.f};  // pinned zero C-operand
  asm volatile("" : "+v"(zero4));

  float4 nxt = *(const float4*)(xbase + (size_t)0 * G4 + u_own * 4);
  const int b2k = 2 * kg;

  for (int tt = 0; tt < CS; ++tt) {
    float z0, z1, z2, z3;
#pragma unroll
    for (int w = 0; w < 4; ++w) {
      f32x4 a0, a1, a2, a3;
      a0 = __builtin_amdgcn_mfma_f32_16x16x32_f16(au[w][0][0].h, bf0.h, zero4, 0, 0, 0);
      a1 = __builtin_amdgcn_mfma_f32_16x16x32_f16(au[w][1][0].h, bf0.h, zero4, 0, 0, 0);
      a2 = __builtin_amdgcn_mfma_f32_16x16x32_f16(au[w][2][0].h, bf0.h, zero4, 0, 0, 0);
      a3 = __builtin_amdgcn_mfma_f32_16x16x32_f16(au[w][3][0].h, bf0.h, zero4, 0, 0, 0);
      a0 = __builtin_amdgcn_mfma_f32_16x16x32_f16(au[w][0][1].h, bf1.h, a0, 0, 0, 0);
      a1 = __builtin_amdgcn_mfma_f32_16x16x32_f16(au[w][1][1].h, bf1.h, a1, 0, 0, 0);
      a2 = __builtin_amdgcn_mfma_f32_16x16x32_f16(au[w][2][1].h, bf1.h, a2, 0, 0, 0);
      a3 = __builtin_amdgcn_mfma_f32_16x16x32_f16(au[w][3][1].h, bf1.h, a3, 0, 0, 0);

      // select tau = n&3 (3 cndmask/comp), then merge group w (1/comp)
      const bool se = ((n & 1) == 0);
      const bool s01 = ((n & 2) == 0);
      float s0, s1, s2, s3;
      {
        float lo, hi;
        lo = se ? a0[0] : a1[0]; hi = se ? a2[0] : a3[0]; s0 = s01 ? lo : hi;
        lo = se ? a0[1] : a1[1]; hi = se ? a2[1] : a3[1]; s1 = s01 ? lo : hi;
        lo = se ? a0[2] : a1[2]; hi = se ? a2[2] : a3[2]; s2 = s01 ? lo : hi;
        lo = se ? a0[3] : a1[3]; hi = se ? a2[3] : a3[3]; s3 = s01 ? lo : hi;
      }
      if (w == 0) {
        z0 = s0; z1 = s1; z2 = s2; z3 = s3;
      } else {
        const bool gs = (grp == w);
        z0 = gs ? s0 : z0; z1 = gs ? s1 : z1;
        z2 = gs ? s2 : z2; z3 = gs ? s3 : z3;
      }
    }
    z0 += nxt.x; z1 += nxt.y; z2 += nxt.z; z3 += nxt.w;

    const int tn = (tt + 1 < CS) ? (tt + 1) : tt;
    nxt = *(const float4*)(xbase + (size_t)tn * G4 + u_own * 4);  // prefetch

    // Scaled activations (scales folded into weights/xw upstream).
    const float gi = __builtin_amdgcn_rcpf(1.f + __builtin_amdgcn_exp2f(z0));
    const float gf = __builtin_amdgcn_rcpf(1.f + __builtin_amdgcn_exp2f(z1));
    const float gg =
        fmaf(-2.f, __builtin_amdgcn_rcpf(1.f + __builtin_amdgcn_exp2f(z2)), 1.f);
    const float go = __builtin_amdgcn_rcpf(1.f + __builtin_amdgcn_exp2f(z3));
    c = fmaf(gf, c, gi * gg);
    const float th = fmaf(
        -2.f,
        __builtin_amdgcn_rcpf(1.f + __builtin_amdgcn_exp2f(c * (2.f * LOG2E))),
        1.f);
    const float h = go * th;

    const int s = t0 + tt;
    if (role < 2) {
      hout[(size_t)s * H + u_own] = (__fp16)h;  // fire-and-forget f16
    } else if (s == T - 1) {
      h3out[u_own] = h;
    }

    // h redistribution: 16 independent intra-wave bpermutes -> B-fragments.
    {
      const float q0 = bperm_f(b2k + 0, h),  q1 = bperm_f(b2k + 16, h);
      const float q2 = bperm_f(b2k + 32, h), q3 = bperm_f(b2k + 48, h);
      const float q4 = bperm_f(b2k + 1, h),  q5 = bperm_f(b2k + 17, h);
      const float q6 = bperm_f(b2k + 33, h), q7 = bperm_f(b2k + 49, h);
      bf0.i = (i32x4){pack_f16(q0, q1), pack_f16(q2, q3),
                      pack_f16(q4, q5), pack_f16(q6, q7)};
      const float r0 = bperm_f(b2k + 8, h),  r1 = bperm_f(b2k + 24, h);
      const float r2 = bperm_f(b2k + 40, h), r3 = bperm_f(b2k + 56, h);
      const float r4 = bperm_f(b2k + 9, h),  r5 = bperm_f(b2k + 25, h);
      const float r6 = bperm_f(b2k + 41, h), r7 = bperm_f(b2k + 57, h);
      bf1.i = (i32x4){pack_f16(r0, r1), pack_f16(r2, r3),
                      pack_f16(r4, r5), pack_f16(r6, r7)};
    }

    if (tt == CS - 1) {  // chunk-boundary state save
      cst[role * 64 + u_own] = c;
      hbnd[role * 64 + u_own] = h;
    }
  }
}

// Dense head: relu(h3@Wd1+bd1) -> relu(@Wd2+bd2) -> @Wl+bl  (all f32)
__global__ __launch_bounds__(64) void head_k(const float* __restrict__ hlast,
                                             const float* __restrict__ Wd1,
                                             const float* __restrict__ bd1,
                                             const float* __restrict__ Wd2,
                                             const float* __restrict__ bd2,
                                             const float* __restrict__ Wl,
                                             const float* __restrict__ bl,
                                             float* __restrict__ out) {
  __shared__ float s_h[H];
  __shared__ float s_a[20];
  __shared__ float s_b[20];
  const int j = threadIdx.x;
  s_h[j] = hlast[j];
  __syncthreads();
  if (j < 20) {
    float acc = bd1[j];
#pragma unroll
    for (int k = 0; k < H; ++k) acc = fmaf(s_h[k], Wd1[k * 20 + j], acc);
    s_a[j] = fmaxf(acc, 0.f);
  }
  __syncthreads();
  if (j < 20) {
    float acc = bd2[j];
#pragma unroll
    for (int k = 0; k < 20; ++k) acc = fmaf(s_a[k], Wd2[k * 20 + j], acc);
    s_b[j] = fmaxf(acc, 0.f);
  }
  __syncthreads();
  if (j < 10) {
    float acc = bl[j];
#pragma unroll
    for (int k = 0; k < 20; ++k) acc = fmaf(s_b[k], Wl[k * 10 + j], acc);
    out[j] = acc;
  }
}

extern "C" void kernel_launch(void* const* d_in, const int* in_sizes, int n_in,
                              void* d_out, int out_size, void* d_ws, size_t ws_size,
                              hipStream_t stream) {
  const float* x   = (const float*)d_in[0];
  const float* W1  = (const float*)d_in[1];
  const float* U1  = (const float*)d_in[2];
  const float* b1  = (const float*)d_in[3];
  const float* W2  = (const float*)d_in[4];
  const float* U2  = (const float*)d_in[5];
  const float* b2  = (const float*)d_in[6];
  const float* W3  = (const float*)d_in[7];
  const float* U3  = (const float*)d_in[8];
  const float* b3  = (const float*)d_in[9];
  const float* Wd1 = (const float*)d_in[10];
  const float* bd1 = (const float*)d_in[11];
  const float* Wd2 = (const float*)d_in[12];
  const float* bd2 = (const float*)d_in[13];
  const float* Wl  = (const float*)d_in[14];
  const float* bl  = (const float*)d_in[15];
  const int T = in_sizes[0] / 2;  // 16384 = NC*CS

  // workspace: xw1 [T,256] f32 | h1s,h2s [T,64] f16 | xw2s,xw3s ring2 |
  //            hbnd [192] f32 | cst [192] f32 | h3out [64] f32   ~23.2MB
  float* xw1 = (float*)d_ws;
  __fp16* h1s = (__fp16*)(xw1 + (size_t)T * G4);
  __fp16* h2s = h1s + (size_t)T * H;
  float* xw2s = (float*)(h2s + (size_t)T * H);
  float* xw3s = xw2s + 2 * CS * G4;
  float* hbnd = xw3s + 2 * CS * G4;
  float* cst = hbnd + 192;
  float* h3out = cst + 192;

  proj_x<<<T, G4, 0, stream>>>(x, W1, b1, xw1);
  for (int q = 0; q < NC + 4; ++q) {
    pipe_step<<<3 + 2 * PB, G4, 0, stream>>>(q, xw1, U1, U2, U3, W2, W3, b2,
                                             b3, h1s, h2s, xw2s, xw3s, hbnd,
                                             cst, h3out, T);
  }
  head_k<<<1, 64, 0, stream>>>(h3out, Wd1, bd1, Wd2, bd2, Wl, bl,
                               (float*)d_out);
}

// Round 19
// 7970.662 us; speedup vs baseline: 1.3749x; 1.3749x over previous
//
#include <hip/hip_runtime.h>

#define H 64
#define G4 256   // 4*H
#define CS 256   // timesteps per chunk (512->256: smaller pipeline fill)
#define NC 64    // chunks: T = NC*CS
#define PB 8     // proj blocks per layer-projection (TPB stays 32)
#define TPB (CS / PB)  // 32 timesteps per proj block
#define LOG2E 1.44269504088896f

typedef _Float16 f16x8 __attribute__((ext_vector_type(8)));
typedef float f32x4 __attribute__((ext_vector_type(4)));
typedef __fp16 p16x2 __attribute__((ext_vector_type(2)));

union I4F { int4 i; f16x8 h; };

__device__ __forceinline__ int pack_f16s(float lo, float hi, float sc) {
  union { p16x2 h; int i; } u;
  u.h = __builtin_amdgcn_cvt_pkrtz(lo * sc, hi * sc);
  return u.i;
}
__device__ __forceinline__ int pack_f16(float lo, float hi) {
  union { p16x2 h; int i; } u;
  u.h = __builtin_amdgcn_cvt_pkrtz(lo, hi);
  return u.i;
}
// Workgroup barrier draining ONLY lgkmcnt (LDS); globals stay in flight.
__device__ __forceinline__ void wg_barrier() {
  asm volatile("s_waitcnt lgkmcnt(0)\n\ts_barrier" ::: "memory");
}

// Input projection, cperm-major (pos = u*4 + G), bias folded, gate-scaled
// (tanh gate ×2log2e, sigmoid gates ×-log2e -> scan uses raw exp2+rcp).
__global__ __launch_bounds__(G4) void proj_x(const float* __restrict__ x,
                                             const float* __restrict__ W,
                                             const float* __restrict__ b,
                                             float* __restrict__ xw) {
  const int t = blockIdx.x;
  const int j = threadIdx.x;  // original column = G*64 + u
  const int G = j >> 6, u = j & 63;
  const float sc = (G == 2) ? 2.f * LOG2E : -LOG2E;
  xw[(size_t)t * G4 + u * 4 + G] =
      sc * fmaf(x[2 * t], W[j], fmaf(x[2 * t + 1], W[G4 + j], b[j]));
}

// One pipeline step (launch q) — round-16-proven structure (8.28 ms), only
// CS halved. All dependencies cross LAUNCH boundaries (full fences).
//   block 0/1/2: scan L0 chunk q / L1 chunk q-2 / L2 chunk q-4
//   blocks 3..10:  proj2 chunk q-1: xw2s = scl*(W2^T h1 + b2)
//   blocks 11..18: proj3 chunk q-3: xw3s = scl*(W3^T h2 + b3)
// Scan engine = 4-wave pure-U MFMA scan (measured 459 ns/step): 8
// mfma_16x16x32_f16, B = own-h f16 from LDS parity buffers, r13-verified
// mapping -> all 4 gates of unit u_own = 16wv+4(n&3)+kg in one lane after a
// 12-cndmask select. W-matvec off the critical path (proj blocks).
// NOTE (r17/r18 lesson): 1-wave variants with all of U in registers are
// SLOWER (600 ns/step) — zero cross-wave latency hiding; and the RA caps
// arch VGPRs ~132, so >64 persistent weight regs/thread is not grantable.
__global__ __attribute__((amdgpu_flat_work_group_size(G4, G4),
                          amdgpu_waves_per_eu(1, 1)))
void pipe_step(int q, const float* __restrict__ xw1,
               const float* __restrict__ U1, const float* __restrict__ U2,
               const float* __restrict__ U3, const float* __restrict__ W2,
               const float* __restrict__ W3, const float* __restrict__ b2,
               const float* __restrict__ b3, __fp16* __restrict__ h1s,
               __fp16* __restrict__ h2s, __fp16* __restrict__ hb3,
               float* __restrict__ xw2s, float* __restrict__ xw3s,
               float* __restrict__ cst, float* __restrict__ h3out, int T) {
  const int bid = (int)blockIdx.x;
  const int tid = (int)threadIdx.x;

  // ================= proj blocks =================
  if (bid >= 3) {
    const int p = bid - 3;
    const int lay = p / PB;             // 0: L1 input, 1: L2 input
    const int pb = p % PB;
    const int chunk = q - 1 - 2 * lay;  // q-1 or q-3
    if (chunk < 0 || chunk >= NC) return;
    const __fp16* hsrc = lay ? h2s : h1s;
    const float* Wm = lay ? W3 : W2;
    const float* bb = lay ? b3 : b2;
    float* dst = (lay ? xw3s : xw2s) + (size_t)(chunk & 1) * CS * G4;
    const int tl0 = pb * TPB;

    __shared__ float sh[TPB * H];
    {  // stage TPB*64 f16 = 4096B = 256 int4: one per thread, cvt to f32
      union { int4 i; __fp16 hh[8]; } uu;
      uu.i = ((const int4*)(hsrc + (size_t)(chunk * CS + tl0) * H))[tid];
      float4 lo = make_float4(uu.hh[0], uu.hh[1], uu.hh[2], uu.hh[3]);
      float4 hi = make_float4(uu.hh[4], uu.hh[5], uu.hh[6], uu.hh[7]);
      ((float4*)sh)[2 * tid] = lo;
      ((float4*)sh)[2 * tid + 1] = hi;
    }
    __syncthreads();

    const int j = tid;
    const int G = j >> 6, u = j & 63;
    const int pos = (u << 2) | G;
    const float scl = (G == 2) ? 2.f * LOG2E : -LOG2E;
    float w[H];
#pragma unroll
    for (int k = 0; k < H; ++k) w[k] = Wm[k * G4 + j];
    const float bj = bb[j];

    for (int tt = 0; tt < TPB; ++tt) {
      const float4* h4 = (const float4*)(sh + tt * H);
      float a0 = bj, a1 = 0.f, a2 = 0.f, a3 = 0.f;
#pragma unroll
      for (int kk = 0; kk < H / 4; ++kk) {
        float4 hv = h4[kk];
        a0 = fmaf(hv.x, w[4 * kk + 0], a0);
        a1 = fmaf(hv.y, w[4 * kk + 1], a1);
        a2 = fmaf(hv.z, w[4 * kk + 2], a2);
        a3 = fmaf(hv.w, w[4 * kk + 3], a3);
      }
      dst[(size_t)(tl0 + tt) * G4 + pos] = scl * ((a0 + a1) + (a2 + a3));
    }
    return;
  }

  // ================= scan blocks (r16-proven 4-wave engine) ============
  const int role = bid;
  const int chunk = q - 2 * role;
  if (chunk < 0 || chunk >= NC) return;
  const int t0 = chunk * CS;

  __shared__ int4 sh_h[2][8];  // [parity][8 int4 = 64 f16 own-h]

  const int wv = tid >> 6;
  const int n = tid & 15;
  const int kg = (tid & 63) >> 4;
  const int u_own = (wv << 4) | ((n & 3) << 2) | kg;

  const float* U = (role == 0) ? U1 : ((role == 1) ? U2 : U3);
  const float scl = ((n & 3) == 2) ? 2.f * LOG2E : -LOG2E;

  // A-fragments (r13-verified), gate-scaled at pack.
  I4F au[4][2];
#pragma unroll
  for (int tau = 0; tau < 4; ++tau) {
    const int colA = ((n & 3) << 6) | (wv << 4) | (tau << 2) | (n >> 2);
#pragma unroll
    for (int kap = 0; kap < 2; ++kap) {
      const int k0 = kap * 32 + kg * 8;
      au[tau][kap].i = make_int4(
          pack_f16s(U[(k0 + 0) * G4 + colA], U[(k0 + 1) * G4 + colA], scl),
          pack_f16s(U[(k0 + 2) * G4 + colA], U[(k0 + 3) * G4 + colA], scl),
          pack_f16s(U[(k0 + 4) * G4 + colA], U[(k0 + 5) * G4 + colA], scl),
          pack_f16s(U[(k0 + 6) * G4 + colA], U[(k0 + 7) * G4 + colA], scl));
      asm volatile("" : "+v"(au[tau][kap].i.x), "+v"(au[tau][kap].i.y),
                       "+v"(au[tau][kap].i.z), "+v"(au[tau][kap].i.w));
    }
  }

  // xw stream base (bias+scale folded for ALL roles), local index tt.
  const float* xbase =
      (role == 0) ? (xw1 + (size_t)t0 * G4)
                  : ((role == 1) ? xw2s : xw3s) + (size_t)(chunk & 1) * CS * G4;
  __fp16* hout = (role == 0) ? h1s : h2s;  // roles 0,1 publish h sequence

  // Cell state + own-h parity init (all cross-launch data).
  float c = (chunk == 0) ? 0.f : cst[role * 64 + u_own];
  if (tid < 8) {
    int4 v = make_int4(0, 0, 0, 0);
    if (chunk > 0) {
      const int4* src = (role == 0)
              ? (const int4*)(h1s + (size_t)(t0 - 1) * H)
              : (role == 1) ? (const int4*)(h2s + (size_t)(t0 - 1) * H)
                            : (const int4*)hb3;
      v = src[tid];
    }
    sh_h[(t0 - 1) & 1][tid] = v;
  }
  wg_barrier();

  float4 nxt = *(const float4*)(xbase + (size_t)0 * G4 + u_own * 4);

  for (int tt = 0; tt < CS; ++tt) {
    const int s = t0 + tt;
    I4F b0, b1;
    b0.i = sh_h[(s - 1) & 1][kg];
    b1.i = sh_h[(s - 1) & 1][4 + kg];

    f32x4 a0 = {0.f, 0.f, 0.f, 0.f}, a1 = a0, a2 = a0, a3 = a0;
    a0 = __builtin_amdgcn_mfma_f32_16x16x32_f16(au[0][0].h, b0.h, a0, 0, 0, 0);
    a1 = __builtin_amdgcn_mfma_f32_16x16x32_f16(au[1][0].h, b0.h, a1, 0, 0, 0);
    a2 = __builtin_amdgcn_mfma_f32_16x16x32_f16(au[2][0].h, b0.h, a2, 0, 0, 0);
    a3 = __builtin_amdgcn_mfma_f32_16x16x32_f16(au[3][0].h, b0.h, a3, 0, 0, 0);
    a0 = __builtin_amdgcn_mfma_f32_16x16x32_f16(au[0][1].h, b1.h, a0, 0, 0, 0);
    a1 = __builtin_amdgcn_mfma_f32_16x16x32_f16(au[1][1].h, b1.h, a1, 0, 0, 0);
    a2 = __builtin_amdgcn_mfma_f32_16x16x32_f16(au[2][1].h, b1.h, a2, 0, 0, 0);
    a3 = __builtin_amdgcn_mfma_f32_16x16x32_f16(au[3][1].h, b1.h, a3, 0, 0, 0);

    // Tile select (tsel = n&3): 3 cndmasks per component.
    const bool se = ((n & 1) == 0);
    const bool s01 = ((n & 2) == 0);
    float z0, z1, z2, z3;
    {
      float lo, hi;
      lo = se ? a0[0] : a1[0]; hi = se ? a2[0] : a3[0]; z0 = s01 ? lo : hi;
      lo = se ? a0[1] : a1[1]; hi = se ? a2[1] : a3[1]; z1 = s01 ? lo : hi;
      lo = se ? a0[2] : a1[2]; hi = se ? a2[2] : a3[2]; z2 = s01 ? lo : hi;
      lo = se ? a0[3] : a1[3]; hi = se ? a2[3] : a3[3]; z3 = s01 ? lo : hi;
    }
    z0 += nxt.x; z1 += nxt.y; z2 += nxt.z; z3 += nxt.w;

    const int tn = (tt + 1 < CS) ? (tt + 1) : tt;
    nxt = *(const float4*)(xbase + (size_t)tn * G4 + u_own * 4);  // prefetch

    // Scaled activations: sigmoid = rcp(1+2^z'), tanh = 1-2*rcp(1+2^z').
    const float gi = __builtin_amdgcn_rcpf(1.f + exp2f(z0));
    const float gf = __builtin_amdgcn_rcpf(1.f + exp2f(z1));
    const float gg = fmaf(-2.f, __builtin_amdgcn_rcpf(1.f + exp2f(z2)), 1.f);
    const float go = __builtin_amdgcn_rcpf(1.f + exp2f(z3));
    c = fmaf(gf, c, gi * gg);
    const float th =
        fmaf(-2.f, __builtin_amdgcn_rcpf(1.f + exp2f(c * (2.f * LOG2E))), 1.f);
    const float h = go * th;

    if (n < 4) {  // unique writer per unit
      ((__fp16*)&sh_h[s & 1][0])[u_own] = (__fp16)h;
      if (role < 2) {
        hout[(size_t)s * H + u_own] = (__fp16)h;  // fire-and-forget
      } else {
        if (tt == CS - 1) hb3[u_own] = (__fp16)h;
        if (s == T - 1) h3out[u_own] = h;
      }
      if (tt == CS - 1) cst[role * 64 + u_own] = c;
    }
    wg_barrier();  // one barrier per step
  }
}

// Dense head: relu(h3@Wd1+bd1) -> relu(@Wd2+bd2) -> @Wl+bl  (all f32)
__global__ __launch_bounds__(64) void head_k(const float* __restrict__ hlast,
                                             const float* __restrict__ Wd1,
                                             const float* __restrict__ bd1,
                                             const float* __restrict__ Wd2,
                                             const float* __restrict__ bd2,
                                             const float* __restrict__ Wl,
                                             const float* __restrict__ bl,
                                             float* __restrict__ out) {
  __shared__ float s_h[H];
  __shared__ float s_a[20];
  __shared__ float s_b[20];
  const int j = threadIdx.x;
  s_h[j] = hlast[j];
  __syncthreads();
  if (j < 20) {
    float acc = bd1[j];
#pragma unroll
    for (int k = 0; k < H; ++k) acc = fmaf(s_h[k], Wd1[k * 20 + j], acc);
    s_a[j] = fmaxf(acc, 0.f);
  }
  __syncthreads();
  if (j < 20) {
    float acc = bd2[j];
#pragma unroll
    for (int k = 0; k < 20; ++k) acc = fmaf(s_a[k], Wd2[k * 20 + j], acc);
    s_b[j] = fmaxf(acc, 0.f);
  }
  __syncthreads();
  if (j < 10) {
    float acc = bl[j];
#pragma unroll
    for (int k = 0; k < 20; ++k) acc = fmaf(s_b[k], Wl[k * 10 + j], acc);
    out[j] = acc;
  }
}

extern "C" void kernel_launch(void* const* d_in, const int* in_sizes, int n_in,
                              void* d_out, int out_size, void* d_ws, size_t ws_size,
                              hipStream_t stream) {
  const float* x   = (const float*)d_in[0];
  const float* W1  = (const float*)d_in[1];
  const float* U1  = (const float*)d_in[2];
  const float* b1  = (const float*)d_in[3];
  const float* W2  = (const float*)d_in[4];
  const float* U2  = (const float*)d_in[5];
  const float* b2  = (const float*)d_in[6];
  const float* W3  = (const float*)d_in[7];
  const float* U3  = (const float*)d_in[8];
  const float* b3  = (const float*)d_in[9];
  const float* Wd1 = (const float*)d_in[10];
  const float* bd1 = (const float*)d_in[11];
  const float* Wd2 = (const float*)d_in[12];
  const float* bd2 = (const float*)d_in[13];
  const float* Wl  = (const float*)d_in[14];
  const float* bl  = (const float*)d_in[15];
  const int T = in_sizes[0] / 2;  // 16384 = NC*CS

  // workspace: xw1 [T,256] f32 | h1s,h2s [T,64] f16 | xw2s,xw3s ring2 |
  //            hb3 [64] f16 | cst [192] f32 | h3out [64] f32
  float* xw1 = (float*)d_ws;
  __fp16* h1s = (__fp16*)(xw1 + (size_t)T * G4);
  __fp16* h2s = h1s + (size_t)T * H;
  float* xw2s = (float*)(h2s + (size_t)T * H);
  float* xw3s = xw2s + 2 * CS * G4;
  __fp16* hb3 = (__fp16*)(xw3s + 2 * CS * G4);
  float* cst = (float*)(hb3 + H);
  float* h3out = cst + 192;

  proj_x<<<T, G4, 0, stream>>>(x, W1, b1, xw1);
  for (int q = 0; q < NC + 4; ++q) {
    pipe_step<<<3 + 2 * PB, G4, 0, stream>>>(q, xw1, U1, U2, U3, W2, W3, b2,
                                             b3, h1s, h2s, hb3, xw2s, xw3s,
                                             cst, h3out, T);
  }
  head_k<<<1, 64, 0, stream>>>(h3out, Wd1, bd1, Wd2, bd2, Wl, bl,
                               (float*)d_out);
}

// Round 20
// 6784.489 us; speedup vs baseline: 1.6153x; 1.1748x over previous
//
#include <hip/hip_runtime.h>

#define H 64
#define G4 256   // 4*H
#define CS 128   // timesteps per chunk (256->128: smaller pipeline fill)
#define NC 128   // chunks: T = NC*CS
#define PB 4     // proj blocks per layer-projection (TPB stays 32)
#define TPB (CS / PB)  // 32 timesteps per proj block
#define LOG2E 1.44269504088896f

typedef _Float16 f16x8 __attribute__((ext_vector_type(8)));
typedef float f32x4 __attribute__((ext_vector_type(4)));
typedef __fp16 p16x2 __attribute__((ext_vector_type(2)));

union I4F { int4 i; f16x8 h; };

__device__ __forceinline__ int pack_f16s(float lo, float hi, float sc) {
  union { p16x2 h; int i; } u;
  u.h = __builtin_amdgcn_cvt_pkrtz(lo * sc, hi * sc);
  return u.i;
}
__device__ __forceinline__ int pack_f16(float lo, float hi) {
  union { p16x2 h; int i; } u;
  u.h = __builtin_amdgcn_cvt_pkrtz(lo, hi);
  return u.i;
}
// Workgroup barrier draining ONLY lgkmcnt (LDS); globals stay in flight.
__device__ __forceinline__ void wg_barrier() {
  asm volatile("s_waitcnt lgkmcnt(0)\n\ts_barrier" ::: "memory");
}

// Input projection, cperm-major (pos = u*4 + G), bias folded, gate-scaled
// (tanh gate ×2log2e, sigmoid gates ×-log2e -> scan uses raw exp2+rcp).
__global__ __launch_bounds__(G4) void proj_x(const float* __restrict__ x,
                                             const float* __restrict__ W,
                                             const float* __restrict__ b,
                                             float* __restrict__ xw) {
  const int t = blockIdx.x;
  const int j = threadIdx.x;  // original column = G*64 + u
  const int G = j >> 6, u = j & 63;
  const float sc = (G == 2) ? 2.f * LOG2E : -LOG2E;
  xw[(size_t)t * G4 + u * 4 + G] =
      sc * fmaf(x[2 * t], W[j], fmaf(x[2 * t + 1], W[G4 + j], b[j]));
}

// One pipeline step (launch q) — r16/r19-proven structure; CS=128 and
// xw folded into the MFMA C-operand (removes 4 adds from the post-select
// critical path; seeds prefetched off-path).
//   block 0/1/2: scan L0 chunk q / L1 chunk q-2 / L2 chunk q-4
//   blocks 3..6:  proj2 chunk q-1: xw2s = scl*(W2^T h1 + b2)
//   blocks 7..10: proj3 chunk q-3: xw3s = scl*(W3^T h2 + b3)
// Scan engine: 4-wave pure-U MFMA scan — 8 mfma_16x16x32_f16 (C seeded
// with the tile's xw float4), B = own-h f16 from LDS parity buffers,
// r13-verified mapping -> 4 gates of unit u_own=(wv<<4)|4(n&3)+kg in one
// lane after a 12-cndmask select. W-matvec off critical path (proj blocks).
// Model: total = T*step + 4*CS*step; step ~460ns is the structural floor
// (r17/r18: no-barrier single-wave = 600ns; exchange+barrier irreducible).
__global__ __attribute__((amdgpu_flat_work_group_size(G4, G4),
                          amdgpu_waves_per_eu(1, 1)))
void pipe_step(int q, const float* __restrict__ xw1,
               const float* __restrict__ U1, const float* __restrict__ U2,
               const float* __restrict__ U3, const float* __restrict__ W2,
               const float* __restrict__ W3, const float* __restrict__ b2,
               const float* __restrict__ b3, __fp16* __restrict__ h1s,
               __fp16* __restrict__ h2s, __fp16* __restrict__ hb3,
               float* __restrict__ xw2s, float* __restrict__ xw3s,
               float* __restrict__ cst, float* __restrict__ h3out, int T) {
  const int bid = (int)blockIdx.x;
  const int tid = (int)threadIdx.x;

  // ================= proj blocks =================
  if (bid >= 3) {
    const int p = bid - 3;
    const int lay = p / PB;             // 0: L1 input, 1: L2 input
    const int pb = p % PB;
    const int chunk = q - 1 - 2 * lay;  // q-1 or q-3
    if (chunk < 0 || chunk >= NC) return;
    const __fp16* hsrc = lay ? h2s : h1s;
    const float* Wm = lay ? W3 : W2;
    const float* bb = lay ? b3 : b2;
    float* dst = (lay ? xw3s : xw2s) + (size_t)(chunk & 1) * CS * G4;
    const int tl0 = pb * TPB;

    __shared__ float sh[TPB * H];
    {  // stage TPB*64 f16 = 4096B = 256 int4: one per thread, cvt to f32
      union { int4 i; __fp16 hh[8]; } uu;
      uu.i = ((const int4*)(hsrc + (size_t)(chunk * CS + tl0) * H))[tid];
      float4 lo = make_float4(uu.hh[0], uu.hh[1], uu.hh[2], uu.hh[3]);
      float4 hi = make_float4(uu.hh[4], uu.hh[5], uu.hh[6], uu.hh[7]);
      ((float4*)sh)[2 * tid] = lo;
      ((float4*)sh)[2 * tid + 1] = hi;
    }
    __syncthreads();

    const int j = tid;
    const int G = j >> 6, u = j & 63;
    const int pos = (u << 2) | G;
    const float scl = (G == 2) ? 2.f * LOG2E : -LOG2E;
    float w[H];
#pragma unroll
    for (int k = 0; k < H; ++k) w[k] = Wm[k * G4 + j];
    const float bj = bb[j];

    for (int tt = 0; tt < TPB; ++tt) {
      const float4* h4 = (const float4*)(sh + tt * H);
      float a0 = bj, a1 = 0.f, a2 = 0.f, a3 = 0.f;
#pragma unroll
      for (int kk = 0; kk < H / 4; ++kk) {
        float4 hv = h4[kk];
        a0 = fmaf(hv.x, w[4 * kk + 0], a0);
        a1 = fmaf(hv.y, w[4 * kk + 1], a1);
        a2 = fmaf(hv.z, w[4 * kk + 2], a2);
        a3 = fmaf(hv.w, w[4 * kk + 3], a3);
      }
      dst[(size_t)(tl0 + tt) * G4 + pos] = scl * ((a0 + a1) + (a2 + a3));
    }
    return;
  }

  // ================= scan blocks (4-wave engine, C-seeded) ============
  const int role = bid;
  const int chunk = q - 2 * role;
  if (chunk < 0 || chunk >= NC) return;
  const int t0 = chunk * CS;

  __shared__ int4 sh_h[2][8];  // [parity][8 int4 = 64 f16 own-h]

  const int wv = tid >> 6;
  const int n = tid & 15;
  const int kg = (tid & 63) >> 4;
  const int u_own = (wv << 4) | ((n & 3) << 2) | kg;

  const float* U = (role == 0) ? U1 : ((role == 1) ? U2 : U3);
  const float scl = ((n & 3) == 2) ? 2.f * LOG2E : -LOG2E;

  // A-fragments (r13-verified), gate-scaled at pack.
  I4F au[4][2];
#pragma unroll
  for (int tau = 0; tau < 4; ++tau) {
    const int colA = ((n & 3) << 6) | (wv << 4) | (tau << 2) | (n >> 2);
#pragma unroll
    for (int kap = 0; kap < 2; ++kap) {
      const int k0 = kap * 32 + kg * 8;
      au[tau][kap].i = make_int4(
          pack_f16s(U[(k0 + 0) * G4 + colA], U[(k0 + 1) * G4 + colA], scl),
          pack_f16s(U[(k0 + 2) * G4 + colA], U[(k0 + 3) * G4 + colA], scl),
          pack_f16s(U[(k0 + 4) * G4 + colA], U[(k0 + 5) * G4 + colA], scl),
          pack_f16s(U[(k0 + 6) * G4 + colA], U[(k0 + 7) * G4 + colA], scl));
      asm volatile("" : "+v"(au[tau][kap].i.x), "+v"(au[tau][kap].i.y),
                       "+v"(au[tau][kap].i.z), "+v"(au[tau][kap].i.w));
    }
  }

  // xw stream base (bias+scale folded for ALL roles), local index tt.
  const float* xbase =
      (role == 0) ? (xw1 + (size_t)t0 * G4)
                  : ((role == 1) ? xw2s : xw3s) + (size_t)(chunk & 1) * CS * G4;
  __fp16* hout = (role == 0) ? h1s : h2s;  // roles 0,1 publish h sequence

  // Cell state + own-h parity init (all cross-launch data).
  float c = (chunk == 0) ? 0.f : cst[role * 64 + u_own];
  if (tid < 8) {
    int4 v = make_int4(0, 0, 0, 0);
    if (chunk > 0) {
      const int4* src = (role == 0)
              ? (const int4*)(h1s + (size_t)(t0 - 1) * H)
              : (role == 1) ? (const int4*)(h2s + (size_t)(t0 - 1) * H)
                            : (const int4*)hb3;
      v = src[tid];
    }
    sh_h[(t0 - 1) & 1][tid] = v;
  }
  wg_barrier();

  // Per-tile xw seeds: tile tau covers unit utau = (wv<<4)|(tau<<2)|kg;
  // its accum f32x4 maps exactly to xw[t][utau*4 .. +4] (cperm layout).
  // Seeding the first MFMA's C with these removes the post-select adds
  // from the critical path; loads prefetch one step ahead (off-path).
  const int us0 = (wv << 4) | kg;  // tau=0 unit; tau adds 4*tau
  f32x4 sd0, sd1, sd2, sd3;
  {
    const float* r0 = xbase + (size_t)0 * G4;
    sd0 = *(const f32x4*)(r0 + (us0 + 0) * 4);
    sd1 = *(const f32x4*)(r0 + (us0 + 4) * 4);
    sd2 = *(const f32x4*)(r0 + (us0 + 8) * 4);
    sd3 = *(const f32x4*)(r0 + (us0 + 12) * 4);
  }

  for (int tt = 0; tt < CS; ++tt) {
    const int s = t0 + tt;
    I4F b0, b1;
    b0.i = sh_h[(s - 1) & 1][kg];
    b1.i = sh_h[(s - 1) & 1][4 + kg];

    f32x4 a0 = __builtin_amdgcn_mfma_f32_16x16x32_f16(au[0][0].h, b0.h, sd0, 0, 0, 0);
    f32x4 a1 = __builtin_amdgcn_mfma_f32_16x16x32_f16(au[1][0].h, b0.h, sd1, 0, 0, 0);
    f32x4 a2 = __builtin_amdgcn_mfma_f32_16x16x32_f16(au[2][0].h, b0.h, sd2, 0, 0, 0);
    f32x4 a3 = __builtin_amdgcn_mfma_f32_16x16x32_f16(au[3][0].h, b0.h, sd3, 0, 0, 0);
    a0 = __builtin_amdgcn_mfma_f32_16x16x32_f16(au[0][1].h, b1.h, a0, 0, 0, 0);
    a1 = __builtin_amdgcn_mfma_f32_16x16x32_f16(au[1][1].h, b1.h, a1, 0, 0, 0);
    a2 = __builtin_amdgcn_mfma_f32_16x16x32_f16(au[2][1].h, b1.h, a2, 0, 0, 0);
    a3 = __builtin_amdgcn_mfma_f32_16x16x32_f16(au[3][1].h, b1.h, a3, 0, 0, 0);

    // prefetch next step's seeds (off critical path)
    const int tn = (tt + 1 < CS) ? (tt + 1) : tt;
    {
      const float* rn = xbase + (size_t)tn * G4;
      sd0 = *(const f32x4*)(rn + (us0 + 0) * 4);
      sd1 = *(const f32x4*)(rn + (us0 + 4) * 4);
      sd2 = *(const f32x4*)(rn + (us0 + 8) * 4);
      sd3 = *(const f32x4*)(rn + (us0 + 12) * 4);
    }

    // Tile select (tsel = n&3): 3 cndmasks per component; xw already in.
    const bool se = ((n & 1) == 0);
    const bool s01 = ((n & 2) == 0);
    float z0, z1, z2, z3;
    {
      float lo, hi;
      lo = se ? a0[0] : a1[0]; hi = se ? a2[0] : a3[0]; z0 = s01 ? lo : hi;
      lo = se ? a0[1] : a1[1]; hi = se ? a2[1] : a3[1]; z1 = s01 ? lo : hi;
      lo = se ? a0[2] : a1[2]; hi = se ? a2[2] : a3[2]; z2 = s01 ? lo : hi;
      lo = se ? a0[3] : a1[3]; hi = se ? a2[3] : a3[3]; z3 = s01 ? lo : hi;
    }

    // Scaled activations: sigmoid = rcp(1+2^z'), tanh = 1-2*rcp(1+2^z').
    const float gi = __builtin_amdgcn_rcpf(1.f + exp2f(z0));
    const float gf = __builtin_amdgcn_rcpf(1.f + exp2f(z1));
    const float gg = fmaf(-2.f, __builtin_amdgcn_rcpf(1.f + exp2f(z2)), 1.f);
    const float go = __builtin_amdgcn_rcpf(1.f + exp2f(z3));
    c = fmaf(gf, c, gi * gg);
    const float th =
        fmaf(-2.f, __builtin_amdgcn_rcpf(1.f + exp2f(c * (2.f * LOG2E))), 1.f);
    const float h = go * th;

    if (n < 4) {  // unique writer per unit
      ((__fp16*)&sh_h[s & 1][0])[u_own] = (__fp16)h;
      if (role < 2) {
        hout[(size_t)s * H + u_own] = (__fp16)h;  // fire-and-forget
      } else {
        if (tt == CS - 1) hb3[u_own] = (__fp16)h;
        if (s == T - 1) h3out[u_own] = h;
      }
      if (tt == CS - 1) cst[role * 64 + u_own] = c;
    }
    wg_barrier();  // one barrier per step
  }
}

// Dense head: relu(h3@Wd1+bd1) -> relu(@Wd2+bd2) -> @Wl+bl  (all f32)
__global__ __launch_bounds__(64) void head_k(const float* __restrict__ hlast,
                                             const float* __restrict__ Wd1,
                                             const float* __restrict__ bd1,
                                             const float* __restrict__ Wd2,
                                             const float* __restrict__ bd2,
                                             const float* __restrict__ Wl,
                                             const float* __restrict__ bl,
                                             float* __restrict__ out) {
  __shared__ float s_h[H];
  __shared__ float s_a[20];
  __shared__ float s_b[20];
  const int j = threadIdx.x;
  s_h[j] = hlast[j];
  __syncthreads();
  if (j < 20) {
    float acc = bd1[j];
#pragma unroll
    for (int k = 0; k < H; ++k) acc = fmaf(s_h[k], Wd1[k * 20 + j], acc);
    s_a[j] = fmaxf(acc, 0.f);
  }
  __syncthreads();
  if (j < 20) {
    float acc = bd2[j];
#pragma unroll
    for (int k = 0; k < 20; ++k) acc = fmaf(s_a[k], Wd2[k * 20 + j], acc);
    s_b[j] = fmaxf(acc, 0.f);
  }
  __syncthreads();
  if (j < 10) {
    float acc = bl[j];
#pragma unroll
    for (int k = 0; k < 20; ++k) acc = fmaf(s_b[k], Wl[k * 10 + j], acc);
    out[j] = acc;
  }
}

extern "C" void kernel_launch(void* const* d_in, const int* in_sizes, int n_in,
                              void* d_out, int out_size, void* d_ws, size_t ws_size,
                              hipStream_t stream) {
  const float* x   = (const float*)d_in[0];
  const float* W1  = (const float*)d_in[1];
  const float* U1  = (const float*)d_in[2];
  const float* b1  = (const float*)d_in[3];
  const float* W2  = (const float*)d_in[4];
  const float* U2  = (const float*)d_in[5];
  const float* b2  = (const float*)d_in[6];
  const float* W3  = (const float*)d_in[7];
  const float* U3  = (const float*)d_in[8];
  const float* b3  = (const float*)d_in[9];
  const float* Wd1 = (const float*)d_in[10];
  const float* bd1 = (const float*)d_in[11];
  const float* Wd2 = (const float*)d_in[12];
  const float* bd2 = (const float*)d_in[13];
  const float* Wl  = (const float*)d_in[14];
  const float* bl  = (const float*)d_in[15];
  const int T = in_sizes[0] / 2;  // 16384 = NC*CS

  // workspace: xw1 [T,256] f32 | h1s,h2s [T,64] f16 | xw2s,xw3s ring2 |
  //            hb3 [64] f16 | cst [192] f32 | h3out [64] f32
  float* xw1 = (float*)d_ws;
  __fp16* h1s = (__fp16*)(xw1 + (size_t)T * G4);
  __fp16* h2s = h1s + (size_t)T * H;
  float* xw2s = (float*)(h2s + (size_t)T * H);
  float* xw3s = xw2s + 2 * CS * G4;
  __fp16* hb3 = (__fp16*)(xw3s + 2 * CS * G4);
  float* cst = (float*)(hb3 + H);
  float* h3out = cst + 192;

  proj_x<<<T, G4, 0, stream>>>(x, W1, b1, xw1);
  for (int q = 0; q < NC + 4; ++q) {
    pipe_step<<<3 + 2 * PB, G4, 0, stream>>>(q, xw1, U1, U2, U3, W2, W3, b2,
                                             b3, h1s, h2s, hb3, xw2s, xw3s,
                                             cst, h3out, T);
  }
  head_k<<<1, 64, 0, stream>>>(h3out, Wd1, bd1, Wd2, bd2, Wl, bl,
                               (float*)d_out);
}

// Round 21
// 6629.262 us; speedup vs baseline: 1.6531x; 1.0234x over previous
//
#include <hip/hip_runtime.h>

#define H 64
#define G4 256   // 4*H
#define CS 64    // timesteps per chunk (128->64: smaller pipeline fill)
#define NC 256   // chunks: T = NC*CS
#define PB 2     // proj blocks per layer-projection (TPB stays 32)
#define TPB (CS / PB)  // 32 timesteps per proj block
#define LOG2E 1.44269504088896f

typedef _Float16 f16x8 __attribute__((ext_vector_type(8)));
typedef float f32x4 __attribute__((ext_vector_type(4)));
typedef __fp16 p16x2 __attribute__((ext_vector_type(2)));

union I4F { int4 i; f16x8 h; };

__device__ __forceinline__ int pack_f16s(float lo, float hi, float sc) {
  union { p16x2 h; int i; } u;
  u.h = __builtin_amdgcn_cvt_pkrtz(lo * sc, hi * sc);
  return u.i;
}
__device__ __forceinline__ int pack_f16(float lo, float hi) {
  union { p16x2 h; int i; } u;
  u.h = __builtin_amdgcn_cvt_pkrtz(lo, hi);
  return u.i;
}
// Workgroup barrier draining ONLY lgkmcnt (LDS); globals stay in flight.
__device__ __forceinline__ void wg_barrier() {
  asm volatile("s_waitcnt lgkmcnt(0)\n\ts_barrier" ::: "memory");
}

// Input projection, cperm-major (pos = u*4 + G), bias folded, gate-scaled
// (tanh gate ×2log2e, sigmoid gates ×-log2e -> scan uses raw exp2+rcp).
__global__ __launch_bounds__(G4) void proj_x(const float* __restrict__ x,
                                             const float* __restrict__ W,
                                             const float* __restrict__ b,
                                             float* __restrict__ xw) {
  const int t = blockIdx.x;
  const int j = threadIdx.x;  // original column = G*64 + u
  const int G = j >> 6, u = j & 63;
  const float sc = (G == 2) ? 2.f * LOG2E : -LOG2E;
  xw[(size_t)t * G4 + u * 4 + G] =
      sc * fmaf(x[2 * t], W[j], fmaf(x[2 * t + 1], W[G4 + j], b[j]));
}

// One pipeline step (launch q) — r16/r20-proven structure; CS=64,
// PARALLEL K-tile MFMAs (chain 2L_mfma -> L_mfma+add), scaled cell state
// c' = 2log2e*c (shortens the tanh tail), h = fmaf(-2go, r, go).
//   block 0/1/2: scan L0 chunk q / L1 chunk q-2 / L2 chunk q-4
//   blocks 3..4: proj2 chunk q-1   blocks 5..6: proj3 chunk q-3
// Scan engine: 4-wave pure-U MFMA scan — 8 mfma_16x16x32_f16 (first set
// C-seeded with xw, second set zero-seeded, summed), B = own-h f16 from
// LDS parity buffers, r13-verified mapping -> 4 gates of unit
// u_own=(wv<<4)|4(n&3)+kg in one lane after a 12-cndmask select.
// Model: total = T*step + 4*CS*step + launches*delta (delta ~0.07us).
__global__ __attribute__((amdgpu_flat_work_group_size(G4, G4),
                          amdgpu_waves_per_eu(1, 1)))
void pipe_step(int q, const float* __restrict__ xw1,
               const float* __restrict__ U1, const float* __restrict__ U2,
               const float* __restrict__ U3, const float* __restrict__ W2,
               const float* __restrict__ W3, const float* __restrict__ b2,
               const float* __restrict__ b3, __fp16* __restrict__ h1s,
               __fp16* __restrict__ h2s, __fp16* __restrict__ hb3,
               float* __restrict__ xw2s, float* __restrict__ xw3s,
               float* __restrict__ cst, float* __restrict__ h3out, int T) {
  const int bid = (int)blockIdx.x;
  const int tid = (int)threadIdx.x;

  // ================= proj blocks =================
  if (bid >= 3) {
    const int p = bid - 3;
    const int lay = p / PB;             // 0: L1 input, 1: L2 input
    const int pb = p % PB;
    const int chunk = q - 1 - 2 * lay;  // q-1 or q-3
    if (chunk < 0 || chunk >= NC) return;
    const __fp16* hsrc = lay ? h2s : h1s;
    const float* Wm = lay ? W3 : W2;
    const float* bb = lay ? b3 : b2;
    float* dst = (lay ? xw3s : xw2s) + (size_t)(chunk & 1) * CS * G4;
    const int tl0 = pb * TPB;

    __shared__ float sh[TPB * H];
    {  // stage TPB*64 f16 = 4096B = 256 int4: one per thread, cvt to f32
      union { int4 i; __fp16 hh[8]; } uu;
      uu.i = ((const int4*)(hsrc + (size_t)(chunk * CS + tl0) * H))[tid];
      float4 lo = make_float4(uu.hh[0], uu.hh[1], uu.hh[2], uu.hh[3]);
      float4 hi = make_float4(uu.hh[4], uu.hh[5], uu.hh[6], uu.hh[7]);
      ((float4*)sh)[2 * tid] = lo;
      ((float4*)sh)[2 * tid + 1] = hi;
    }
    __syncthreads();

    const int j = tid;
    const int G = j >> 6, u = j & 63;
    const int pos = (u << 2) | G;
    const float scl = (G == 2) ? 2.f * LOG2E : -LOG2E;
    float w[H];
#pragma unroll
    for (int k = 0; k < H; ++k) w[k] = Wm[k * G4 + j];
    const float bj = bb[j];

    for (int tt = 0; tt < TPB; ++tt) {
      const float4* h4 = (const float4*)(sh + tt * H);
      float a0 = bj, a1 = 0.f, a2 = 0.f, a3 = 0.f;
#pragma unroll
      for (int kk = 0; kk < H / 4; ++kk) {
        float4 hv = h4[kk];
        a0 = fmaf(hv.x, w[4 * kk + 0], a0);
        a1 = fmaf(hv.y, w[4 * kk + 1], a1);
        a2 = fmaf(hv.z, w[4 * kk + 2], a2);
        a3 = fmaf(hv.w, w[4 * kk + 3], a3);
      }
      dst[(size_t)(tl0 + tt) * G4 + pos] = scl * ((a0 + a1) + (a2 + a3));
    }
    return;
  }

  // ================= scan blocks (4-wave engine) ============
  const int role = bid;
  const int chunk = q - 2 * role;
  if (chunk < 0 || chunk >= NC) return;
  const int t0 = chunk * CS;

  __shared__ int4 sh_h[2][8];  // [parity][8 int4 = 64 f16 own-h]

  const int wv = tid >> 6;
  const int n = tid & 15;
  const int kg = (tid & 63) >> 4;
  const int u_own = (wv << 4) | ((n & 3) << 2) | kg;

  const float* U = (role == 0) ? U1 : ((role == 1) ? U2 : U3);
  const float scl = ((n & 3) == 2) ? 2.f * LOG2E : -LOG2E;

  // A-fragments (r13-verified), gate-scaled at pack.
  I4F au[4][2];
#pragma unroll
  for (int tau = 0; tau < 4; ++tau) {
    const int colA = ((n & 3) << 6) | (wv << 4) | (tau << 2) | (n >> 2);
#pragma unroll
    for (int kap = 0; kap < 2; ++kap) {
      const int k0 = kap * 32 + kg * 8;
      au[tau][kap].i = make_int4(
          pack_f16s(U[(k0 + 0) * G4 + colA], U[(k0 + 1) * G4 + colA], scl),
          pack_f16s(U[(k0 + 2) * G4 + colA], U[(k0 + 3) * G4 + colA], scl),
          pack_f16s(U[(k0 + 4) * G4 + colA], U[(k0 + 5) * G4 + colA], scl),
          pack_f16s(U[(k0 + 6) * G4 + colA], U[(k0 + 7) * G4 + colA], scl));
      asm volatile("" : "+v"(au[tau][kap].i.x), "+v"(au[tau][kap].i.y),
                       "+v"(au[tau][kap].i.z), "+v"(au[tau][kap].i.w));
    }
  }

  // xw stream base (bias+scale folded for ALL roles), local index tt.
  const float* xbase =
      (role == 0) ? (xw1 + (size_t)t0 * G4)
                  : ((role == 1) ? xw2s : xw3s) + (size_t)(chunk & 1) * CS * G4;
  __fp16* hout = (role == 0) ? h1s : h2s;  // roles 0,1 publish h sequence

  // Cell state (stored SCALED: cp = 2log2e * c) + own-h parity init.
  float cp = (chunk == 0) ? 0.f : cst[role * 64 + u_own];
  if (tid < 8) {
    int4 v = make_int4(0, 0, 0, 0);
    if (chunk > 0) {
      const int4* src = (role == 0)
              ? (const int4*)(h1s + (size_t)(t0 - 1) * H)
              : (role == 1) ? (const int4*)(h2s + (size_t)(t0 - 1) * H)
                            : (const int4*)hb3;
      v = src[tid];
    }
    sh_h[(t0 - 1) & 1][tid] = v;
  }
  wg_barrier();

  // Per-tile xw seeds (cperm layout: tile tau's accum f32x4 = that unit's
  // xw float4). Seeds prefetched one step ahead (off critical path).
  const int us0 = (wv << 4) | kg;
  f32x4 sd0, sd1, sd2, sd3;
  {
    const float* r0 = xbase;
    sd0 = *(const f32x4*)(r0 + (us0 + 0) * 4);
    sd1 = *(const f32x4*)(r0 + (us0 + 4) * 4);
    sd2 = *(const f32x4*)(r0 + (us0 + 8) * 4);
    sd3 = *(const f32x4*)(r0 + (us0 + 12) * 4);
  }
  f32x4 zero4 = {0.f, 0.f, 0.f, 0.f};  // pinned zero C-operand
  asm volatile("" : "+v"(zero4));

#pragma unroll 2
  for (int tt = 0; tt < CS; ++tt) {
    const int s = t0 + tt;
    I4F b0, b1;
    b0.i = sh_h[(s - 1) & 1][kg];
    b1.i = sh_h[(s - 1) & 1][4 + kg];

    // Parallel K-tiles: first set C-seeded with xw, second zero-seeded.
    f32x4 a0 = __builtin_amdgcn_mfma_f32_16x16x32_f16(au[0][0].h, b0.h, sd0, 0, 0, 0);
    f32x4 a1 = __builtin_amdgcn_mfma_f32_16x16x32_f16(au[1][0].h, b0.h, sd1, 0, 0, 0);
    f32x4 a2 = __builtin_amdgcn_mfma_f32_16x16x32_f16(au[2][0].h, b0.h, sd2, 0, 0, 0);
    f32x4 a3 = __builtin_amdgcn_mfma_f32_16x16x32_f16(au[3][0].h, b0.h, sd3, 0, 0, 0);
    f32x4 c0 = __builtin_amdgcn_mfma_f32_16x16x32_f16(au[0][1].h, b1.h, zero4, 0, 0, 0);
    f32x4 c1 = __builtin_amdgcn_mfma_f32_16x16x32_f16(au[1][1].h, b1.h, zero4, 0, 0, 0);
    f32x4 c2 = __builtin_amdgcn_mfma_f32_16x16x32_f16(au[2][1].h, b1.h, zero4, 0, 0, 0);
    f32x4 c3 = __builtin_amdgcn_mfma_f32_16x16x32_f16(au[3][1].h, b1.h, zero4, 0, 0, 0);
    a0 = a0 + c0; a1 = a1 + c1; a2 = a2 + c2; a3 = a3 + c3;

    // prefetch next step's seeds (off critical path)
    const int tn = (tt + 1 < CS) ? (tt + 1) : tt;
    {
      const float* rn = xbase + (size_t)tn * G4;
      sd0 = *(const f32x4*)(rn + (us0 + 0) * 4);
      sd1 = *(const f32x4*)(rn + (us0 + 4) * 4);
      sd2 = *(const f32x4*)(rn + (us0 + 8) * 4);
      sd3 = *(const f32x4*)(rn + (us0 + 12) * 4);
    }

    // Tile select (tsel = n&3): 3 cndmasks per component; xw already in.
    const bool se = ((n & 1) == 0);
    const bool s01 = ((n & 2) == 0);
    float z0, z1, z2, z3;
    {
      float lo, hi;
      lo = se ? a0[0] : a1[0]; hi = se ? a2[0] : a3[0]; z0 = s01 ? lo : hi;
      lo = se ? a0[1] : a1[1]; hi = se ? a2[1] : a3[1]; z1 = s01 ? lo : hi;
      lo = se ? a0[2] : a1[2]; hi = se ? a2[2] : a3[2]; z2 = s01 ? lo : hi;
      lo = se ? a0[3] : a1[3]; hi = se ? a2[3] : a3[3]; z3 = s01 ? lo : hi;
    }

    // Activations on the scaled domain. cp = 2log2e*c is the state:
    //   gi,gf,go = rcp(1+2^z'); gg' = 2log2e*tanh-gate = fmaf(-4L,r2,2L);
    //   cp = fmaf(gf, cp, gi*gg'); h = go - 2go*rcp(1+2^cp).
    const float e0 = __builtin_amdgcn_exp2f(z0);
    const float e1 = __builtin_amdgcn_exp2f(z1);
    const float e2 = __builtin_amdgcn_exp2f(z2);
    const float e3 = __builtin_amdgcn_exp2f(z3);
    const float gi = __builtin_amdgcn_rcpf(1.f + e0);
    const float gf = __builtin_amdgcn_rcpf(1.f + e1);
    const float r2 = __builtin_amdgcn_rcpf(1.f + e2);
    const float go = __builtin_amdgcn_rcpf(1.f + e3);
    const float ggs = fmaf(-4.f * LOG2E, r2, 2.f * LOG2E);
    cp = fmaf(gf, cp, gi * ggs);
    const float go2 = go + go;  // off-chain (go ready before r3)
    const float r3 = __builtin_amdgcn_rcpf(1.f + __builtin_amdgcn_exp2f(cp));
    const float h = fmaf(-go2, r3, go);

    if (n < 4) {  // unique writer per unit
      ((__fp16*)&sh_h[s & 1][0])[u_own] = (__fp16)h;
      if (role < 2) {
        hout[(size_t)s * H + u_own] = (__fp16)h;  // fire-and-forget
      } else {
        if (tt == CS - 1) hb3[u_own] = (__fp16)h;
        if (s == T - 1) h3out[u_own] = h;
      }
      if (tt == CS - 1) cst[role * 64 + u_own] = cp;
    }
    wg_barrier();  // one barrier per step
  }
}

// Dense head: relu(h3@Wd1+bd1) -> relu(@Wd2+bd2) -> @Wl+bl  (all f32)
__global__ __launch_bounds__(64) void head_k(const float* __restrict__ hlast,
                                             const float* __restrict__ Wd1,
                                             const float* __restrict__ bd1,
                                             const float* __restrict__ Wd2,
                                             const float* __restrict__ bd2,
                                             const float* __restrict__ Wl,
                                             const float* __restrict__ bl,
                                             float* __restrict__ out) {
  __shared__ float s_h[H];
  __shared__ float s_a[20];
  __shared__ float s_b[20];
  const int j = threadIdx.x;
  s_h[j] = hlast[j];
  __syncthreads();
  if (j < 20) {
    float acc = bd1[j];
#pragma unroll
    for (int k = 0; k < H; ++k) acc = fmaf(s_h[k], Wd1[k * 20 + j], acc);
    s_a[j] = fmaxf(acc, 0.f);
  }
  __syncthreads();
  if (j < 20) {
    float acc = bd2[j];
#pragma unroll
    for (int k = 0; k < 20; ++k) acc = fmaf(s_a[k], Wd2[k * 20 + j], acc);
    s_b[j] = fmaxf(acc, 0.f);
  }
  __syncthreads();
  if (j < 10) {
    float acc = bl[j];
#pragma unroll
    for (int k = 0; k < 20; ++k) acc = fmaf(s_b[k], Wl[k * 10 + j], acc);
    out[j] = acc;
  }
}

extern "C" void kernel_launch(void* const* d_in, const int* in_sizes, int n_in,
                              void* d_out, int out_size, void* d_ws, size_t ws_size,
                              hipStream_t stream) {
  const float* x   = (const float*)d_in[0];
  const float* W1  = (const float*)d_in[1];
  const float* U1  = (const float*)d_in[2];
  const float* b1  = (const float*)d_in[3];
  const float* W2  = (const float*)d_in[4];
  const float* U2  = (const float*)d_in[5];
  const float* b2  = (const float*)d_in[6];
  const float* W3  = (const float*)d_in[7];
  const float* U3  = (const float*)d_in[8];
  const float* b3  = (const float*)d_in[9];
  const float* Wd1 = (const float*)d_in[10];
  const float* bd1 = (const float*)d_in[11];
  const float* Wd2 = (const float*)d_in[12];
  const float* bd2 = (const float*)d_in[13];
  const float* Wl  = (const float*)d_in[14];
  const float* bl  = (const float*)d_in[15];
  const int T = in_sizes[0] / 2;  // 16384 = NC*CS

  // workspace: xw1 [T,256] f32 | h1s,h2s [T,64] f16 | xw2s,xw3s ring2 |
  //            hb3 [64] f16 | cst [192] f32 | h3out [64] f32
  float* xw1 = (float*)d_ws;
  __fp16* h1s = (__fp16*)(xw1 + (size_t)T * G4);
  __fp16* h2s = h1s + (size_t)T * H;
  float* xw2s = (float*)(h2s + (size_t)T * H);
  float* xw3s = xw2s + 2 * CS * G4;
  __fp16* hb3 = (__fp16*)(xw3s + 2 * CS * G4);
  float* cst = (float*)(hb3 + H);
  float* h3out = cst + 192;

  proj_x<<<T, G4, 0, stream>>>(x, W1, b1, xw1);
  for (int q = 0; q < NC + 4; ++q) {
    pipe_step<<<3 + 2 * PB, G4, 0, stream>>>(q, xw1, U1, U2, U3, W2, W3, b2,
                                             b3, h1s, h2s, hb3, xw2s, xw3s,
                                             cst, h3out, T);
  }
  head_k<<<1, 64, 0, stream>>>(h3out, Wd1, bd1, Wd2, bd2, Wl, bl,
                               (float*)d_out);
}